// Round 2
// baseline (766.889 us; speedup 1.0000x reference)
//
#include <hip/hip_runtime.h>

// ---------------- problem constants ----------------
constexpr int BATCH = 4;
constexpr int HS    = 64;     // H
constexpr int WSZ   = 64;     // W
constexpr int LSEQ  = 4096;   // L = H*W
constexpr int DM    = 96;     // d_model
constexpr int DI    = 192;    // d_inner
constexpr int NS    = 16;     // d_state
constexpr int RK    = 6;      // dt_rank
constexpr int KD    = 4;      // scan directions
constexpr int NCH   = 64;     // chunks along L
constexpr int CLEN  = 64;     // chunk length
constexpr int XDS   = 160;    // packed xdbl row: 4 * [B(16) C(16) dt(6) pad(2)]

// scan index l -> spatial position p (row-major h*64+w), per direction
__device__ __forceinline__ int pos_of(int k, int l) {
  switch (k & 3) {
    case 0: return l;
    case 1: return ((l & 63) << 6) | (l >> 6);          // l = w*H+h -> p = h*W+w
    case 2: return LSEQ - 1 - l;
    default: { int lp = LSEQ - 1 - l; return ((lp & 63) << 6) | (lp >> 6); }
  }
}

// ---------------- generic small-K GEMM: C[M,NN] = A[M,KK] * Bw[NN,KK]^T ----------------
template <int NN, int KK, int TM, int KT>
__launch_bounds__(256)
__global__ void gemm_rt(const float* __restrict__ A, const float* __restrict__ Bw,
                        float* __restrict__ C, int M) {
  constexpr int TN  = 64;
  constexpr int RPT = TM / 16;          // rows per thread
  constexpr int SA  = TM + 2;           // padded stride
  constexpr int KQ  = KT / 4;
  __shared__ float AsT[KT][SA];
  __shared__ float BsT[KT][TN];
  const int t = threadIdx.x;
  const int row0 = blockIdx.y * TM;
  const int col0 = blockIdx.x * TN;
  const int tc = t & 15;        // 16 col groups * 4 cols
  const int tr = t >> 4;        // 16 row groups * RPT rows

  float acc[RPT][4];
  #pragma unroll
  for (int i = 0; i < RPT; ++i)
    { acc[i][0]=0.f; acc[i][1]=0.f; acc[i][2]=0.f; acc[i][3]=0.f; }

  for (int k0 = 0; k0 < KK; k0 += KT) {
    for (int idx = t; idx < TM * KQ; idx += 256) {
      int r = idx / KQ, kq = idx % KQ;
      float4 v = *(const float4*)&A[(size_t)(row0 + r) * KK + k0 + kq * 4];
      AsT[kq*4+0][r] = v.x; AsT[kq*4+1][r] = v.y;
      AsT[kq*4+2][r] = v.z; AsT[kq*4+3][r] = v.w;
    }
    for (int idx = t; idx < TN * KQ; idx += 256) {
      int c = idx / KQ, kq = idx % KQ;
      int col = col0 + c;
      float4 v = make_float4(0.f, 0.f, 0.f, 0.f);
      if (col < NN) v = *(const float4*)&Bw[(size_t)col * KK + k0 + kq * 4];
      BsT[kq*4+0][c] = v.x; BsT[kq*4+1][c] = v.y;
      BsT[kq*4+2][c] = v.z; BsT[kq*4+3][c] = v.w;
    }
    __syncthreads();
    for (int kk = 0; kk < KT; ++kk) {
      float4 bv = *(const float4*)&BsT[kk][tc * 4];
      #pragma unroll
      for (int i = 0; i < RPT; ++i) {
        float a = AsT[kk][tr * RPT + i];
        acc[i][0] += a * bv.x; acc[i][1] += a * bv.y;
        acc[i][2] += a * bv.z; acc[i][3] += a * bv.w;
      }
    }
    __syncthreads();
  }
  int c = col0 + tc * 4;
  if (c < NN) {
    #pragma unroll
    for (int i = 0; i < RPT; ++i) {
      size_t r0 = (size_t)(row0 + tr * RPT + i) * NN + c;
      *(float4*)&C[r0] = make_float4(acc[i][0], acc[i][1], acc[i][2], acc[i][3]);
    }
  }
}

// ---------------- depthwise 3x3 conv + bias + SiLU ----------------
__launch_bounds__(256)
__global__ void conv_silu(const float* __restrict__ xz, const float* __restrict__ cw,
                          const float* __restrict__ cb, float* __restrict__ xc) {
  int idx = blockIdx.x * 256 + threadIdx.x;     // over B*L*DI, grid exact
  int d = idx % DI;
  int p = (idx / DI) % LSEQ;
  int b = idx / (DI * LSEQ);
  int h = p >> 6, w = p & 63;
  float acc = cb[d];
  #pragma unroll
  for (int kh = 0; kh < 3; ++kh) {
    int hh = h + kh - 1;
    if ((unsigned)hh >= (unsigned)HS) continue;
    #pragma unroll
    for (int kw = 0; kw < 3; ++kw) {
      int ww = w + kw - 1;
      if ((unsigned)ww >= (unsigned)WSZ) continue;
      acc += xz[((size_t)b * LSEQ + (hh << 6) + ww) * (2 * DI) + d] * cw[d * 9 + kh * 3 + kw];
    }
  }
  xc[idx] = acc / (1.f + __expf(-acc));   // SiLU
}

// ---------------- build packed weight matrix Wcat[160][192] ----------------
// row j = k*40 + jj:  jj<16 -> Bs row (k*38+6+jj); jj<32 -> Cs row (k*38+22+jj-16);
//                     jj<38 -> dt row (k*38+jj-32); else zero pad
__launch_bounds__(256)
__global__ void build_wcat(const float* __restrict__ xw, float* __restrict__ Wcat) {
  int idx = blockIdx.x * 256 + threadIdx.x;   // < 160*192, grid exact
  int j = idx / DI, col = idx % DI;
  int k = j / 40, jj = j % 40;
  float v = 0.f;
  int src = -1;
  if (jj < 16)      src = k * 38 + 6 + jj;
  else if (jj < 32) src = k * 38 + 22 + (jj - 16);
  else if (jj < 38) src = k * 38 + (jj - 32);
  if (src >= 0) v = xw[(size_t)src * DI + col];
  Wcat[idx] = v;
}

// ---------------- dt rank-6 projection + softplus -> delta[bp][k][d] ----------------
__launch_bounds__(256)
__global__ void dt_softplus(const float* __restrict__ xdbl, const float* __restrict__ dtw,
                            const float* __restrict__ dtb, float* __restrict__ delta) {
  const int t = threadIdx.x;
  const int g = blockIdx.y * 256 + t;    // 0..767 over (k,d)
  const int d = g % DI;
  const int k = g / DI;
  float w[RK];
  #pragma unroll
  for (int r = 0; r < RK; ++r) w[r] = dtw[((size_t)k * DI + d) * RK + r];
  const float bsv = dtb[k * DI + d];
  const int p0 = blockIdx.x * 16;
  for (int j = 0; j < 16; ++j) {
    const size_t bp = p0 + j;
    const float* xr = &xdbl[bp * XDS + k * 40 + 32];
    float s = bsv;
    #pragma unroll
    for (int r = 0; r < RK; ++r) s += w[r] * xr[r];
    float dv = (s > 20.f) ? s : log1pf(__expf(s));
    delta[(bp * KD + k) * DI + d] = dv;
  }
}

// ---------------- scan phase 1: per-chunk local states + sum(delta) ----------------
__launch_bounds__(192)
__global__ void scan_phase1(const float* __restrict__ delta, const float* __restrict__ xc,
                            const float* __restrict__ xdbl, const float* __restrict__ Alog,
                            float* __restrict__ hN, float* __restrict__ sumdB) {
  const int d = threadIdx.x;
  const int ch = blockIdx.x, k = blockIdx.y, b = blockIdx.z;
  const int bk = b * KD + k;
  __shared__ float4 Bsh[CLEN * 4];
  for (int idx = d; idx < CLEN * 4; idx += 192) {
    int j = idx >> 2, q = idx & 3;
    int p = pos_of(k, ch * CLEN + j);
    Bsh[idx] = *(const float4*)&xdbl[(size_t)(b * LSEQ + p) * XDS + k * 40 + q * 4];
  }
  float An[NS];
  {
    const float4* Ap = (const float4*)&Alog[((size_t)k * DI + d) * NS];
    #pragma unroll
    for (int q = 0; q < 4; ++q) {
      float4 a = Ap[q];
      An[q*4+0] = -__expf(a.x); An[q*4+1] = -__expf(a.y);
      An[q*4+2] = -__expf(a.z); An[q*4+3] = -__expf(a.w);
    }
  }
  const float An0 = An[0];
  bool geo = true;
  #pragma unroll
  for (int n = 0; n < NS; ++n)
    geo = geo && (fabsf(An[n] - (n + 1) * An0) <= 1e-3f * fabsf(An[n]));
  __syncthreads();

  float h[NS];
  #pragma unroll
  for (int n = 0; n < NS; ++n) h[n] = 0.f;
  float sumd = 0.f;
  const int l0 = ch * CLEN;
  for (int j = 0; j < CLEN; ++j) {
    const int p = pos_of(k, l0 + j);
    const size_t bp = (size_t)b * LSEQ + p;
    float dl = delta[(bp * KD + k) * DI + d];
    float u  = xc[bp * DI + d];
    float du = dl * u;
    float Bv[NS];
    #pragma unroll
    for (int q = 0; q < 4; ++q) {
      float4 v = Bsh[j * 4 + q];
      Bv[q*4+0] = v.x; Bv[q*4+1] = v.y; Bv[q*4+2] = v.z; Bv[q*4+3] = v.w;
    }
    if (geo) {
      float w = __expf(dl * An0), wp = 1.f;
      #pragma unroll
      for (int n = 0; n < NS; ++n) { wp *= w; h[n] = wp * h[n] + du * Bv[n]; }
    } else {
      #pragma unroll
      for (int n = 0; n < NS; ++n) h[n] = __expf(dl * An[n]) * h[n] + du * Bv[n];
    }
    sumd += dl;
  }
  const size_t o = ((size_t)bk * NCH + ch) * DI + d;
  float4* Hp = (float4*)&hN[o * NS];
  #pragma unroll
  for (int q = 0; q < 4; ++q)
    Hp[q] = make_float4(h[q*4+0], h[q*4+1], h[q*4+2], h[q*4+3]);
  sumdB[o] = sumd;
}

// ---------------- sequential chunk combine (in-place: hN becomes entry states) ----------------
__launch_bounds__(256)
__global__ void chunk_combine(float* __restrict__ hN, const float* __restrict__ sumdB,
                              const float* __restrict__ Alog) {
  const int tid = blockIdx.x * 256 + threadIdx.x;   // over B*K*D*N
  const int n  = tid & 15;
  const int dd = tid >> 4;
  const int d  = dd % DI;
  const int bk = dd / DI;
  const int k  = bk & 3;
  const float An = -__expf(Alog[((size_t)k * DI + d) * NS + n]);
  float h = 0.f;
  for (int c = 0; c < NCH; ++c) {
    const size_t o = ((size_t)bk * NCH + c) * DI + d;
    float tmp = hN[o * NS + n];
    hN[o * NS + n] = h;
    h = tmp + __expf(An * sumdB[o]) * h;
  }
}

// ---------------- scan phase 2: entry state, emit y (merged via atomics) ----------------
__launch_bounds__(192)
__global__ void scan_phase2(const float* __restrict__ delta, const float* __restrict__ xc,
                            const float* __restrict__ xdbl, const float* __restrict__ Alog,
                            const float* __restrict__ hin, float* __restrict__ yg) {
  const int d = threadIdx.x;
  const int ch = blockIdx.x, k = blockIdx.y, b = blockIdx.z;
  const int bk = b * KD + k;
  __shared__ float4 Bsh[CLEN * 8];
  for (int idx = d; idx < CLEN * 8; idx += 192) {
    int j = idx >> 3, q = idx & 7;
    int p = pos_of(k, ch * CLEN + j);
    Bsh[idx] = *(const float4*)&xdbl[(size_t)(b * LSEQ + p) * XDS + k * 40 + q * 4];
  }
  float An[NS];
  {
    const float4* Ap = (const float4*)&Alog[((size_t)k * DI + d) * NS];
    #pragma unroll
    for (int q = 0; q < 4; ++q) {
      float4 a = Ap[q];
      An[q*4+0] = -__expf(a.x); An[q*4+1] = -__expf(a.y);
      An[q*4+2] = -__expf(a.z); An[q*4+3] = -__expf(a.w);
    }
  }
  const float An0 = An[0];
  bool geo = true;
  #pragma unroll
  for (int n = 0; n < NS; ++n)
    geo = geo && (fabsf(An[n] - (n + 1) * An0) <= 1e-3f * fabsf(An[n]));

  float h[NS];
  {
    const size_t o = ((size_t)bk * NCH + ch) * DI + d;
    const float4* Hp = (const float4*)&hin[o * NS];
    #pragma unroll
    for (int q = 0; q < 4; ++q) {
      float4 v = Hp[q];
      h[q*4+0] = v.x; h[q*4+1] = v.y; h[q*4+2] = v.z; h[q*4+3] = v.w;
    }
  }
  __syncthreads();
  const int l0 = ch * CLEN;
  for (int j = 0; j < CLEN; ++j) {
    const int p = pos_of(k, l0 + j);
    const size_t bp = (size_t)b * LSEQ + p;
    float dl = delta[(bp * KD + k) * DI + d];
    float u  = xc[bp * DI + d];
    float du = dl * u;
    float Bv[NS], Cv[NS];
    #pragma unroll
    for (int q = 0; q < 4; ++q) {
      float4 v = Bsh[j * 8 + q];
      Bv[q*4+0] = v.x; Bv[q*4+1] = v.y; Bv[q*4+2] = v.z; Bv[q*4+3] = v.w;
      float4 c4 = Bsh[j * 8 + 4 + q];
      Cv[q*4+0] = c4.x; Cv[q*4+1] = c4.y; Cv[q*4+2] = c4.z; Cv[q*4+3] = c4.w;
    }
    float y = 0.f;
    if (geo) {
      float w = __expf(dl * An0), wp = 1.f;
      #pragma unroll
      for (int n = 0; n < NS; ++n) {
        wp *= w; h[n] = wp * h[n] + du * Bv[n]; y += h[n] * Cv[n];
      }
    } else {
      #pragma unroll
      for (int n = 0; n < NS; ++n) {
        h[n] = __expf(dl * An[n]) * h[n] + du * Bv[n]; y += h[n] * Cv[n];
      }
    }
    atomicAdd(&yg[bp * DI + d], y);
  }
}

// ---------------- direction merge (Ds term) + LayerNorm + SiLU gate ----------------
__launch_bounds__(192)
__global__ void fuse_ln(const float* __restrict__ yg, const float* __restrict__ xc,
                        const float* __restrict__ Ds, const float* __restrict__ xz,
                        const float* __restrict__ lnw, const float* __restrict__ lnb,
                        float* __restrict__ ymul) {
  const int row = blockIdx.x;        // b*L + p
  const int d = threadIdx.x;
  float u = xc[(size_t)row * DI + d];
  float sDs = Ds[d] + Ds[DI + d] + Ds[2 * DI + d] + Ds[3 * DI + d];
  float y = yg[(size_t)row * DI + d] + sDs * u;
  float s1 = y, s2 = y * y;
  #pragma unroll
  for (int off = 32; off; off >>= 1) {
    s1 += __shfl_xor(s1, off);
    s2 += __shfl_xor(s2, off);
  }
  __shared__ float r1[3], r2[3];
  int wid = d >> 6;
  if ((d & 63) == 0) { r1[wid] = s1; r2[wid] = s2; }
  __syncthreads();
  float S1 = r1[0] + r1[1] + r1[2];
  float S2 = r2[0] + r2[1] + r2[2];
  float mu = S1 * (1.f / DI);
  float var = S2 * (1.f / DI) - mu * mu;
  float yn = (y - mu) * rsqrtf(var + 1e-5f) * lnw[d] + lnb[d];
  float zv = xz[(size_t)row * (2 * DI) + DI + d];
  float g = zv / (1.f + __expf(-zv));
  ymul[(size_t)row * DI + d] = yn * g;
}

// ---------------- launcher ----------------
extern "C" void kernel_launch(void* const* d_in, const int* in_sizes, int n_in,
                              void* d_out, int out_size, void* d_ws, size_t ws_size,
                              hipStream_t stream) {
  (void)in_sizes; (void)n_in; (void)out_size; (void)ws_size;
  const float* x          = (const float*)d_in[0];
  const float* in_proj_w  = (const float*)d_in[1];
  const float* conv_w     = (const float*)d_in[2];
  const float* conv_b     = (const float*)d_in[3];
  const float* x_proj_w   = (const float*)d_in[4];
  const float* dt_w       = (const float*)d_in[5];
  const float* dt_b       = (const float*)d_in[6];
  const float* A_logs     = (const float*)d_in[7];
  const float* Ds         = (const float*)d_in[8];
  const float* ln_w       = (const float*)d_in[9];
  const float* ln_b       = (const float*)d_in[10];
  const float* out_proj_w = (const float*)d_in[11];
  float* out = (float*)d_out;
  float* ws  = (float*)d_ws;

  constexpr size_t SZ_XZ    = (size_t)BATCH * LSEQ * 2 * DI;
  constexpr size_t SZ_XC    = (size_t)BATCH * LSEQ * DI;
  constexpr size_t SZ_XD    = (size_t)BATCH * LSEQ * XDS;
  constexpr size_t SZ_DELTA = (size_t)BATCH * KD * LSEQ * DI;
  constexpr size_t SZ_HN    = (size_t)BATCH * KD * NCH * DI * NS;
  constexpr size_t SZ_SUMD  = (size_t)BATCH * KD * NCH * DI;

  float* xz    = ws;
  float* xc    = xz + SZ_XZ;
  float* xdbl  = xc + SZ_XC;
  float* delta = xdbl + SZ_XD;
  float* hN    = delta + SZ_DELTA;
  float* sumd  = hN + SZ_HN;
  float* yg    = sumd + SZ_SUMD;
  float* Wcat  = yg + SZ_XC;
  float* ymul  = delta;   // delta dead after scan_phase2

  const int M = BATCH * LSEQ;  // 16384

  // 0. pack x_proj weights for all 4 directions
  build_wcat<<<(XDS * DI) / 256, 256, 0, stream>>>(x_proj_w, Wcat);
  // 1. in_proj: xz[M,384] = x[M,96] @ in_proj_w[384,96]^T
  gemm_rt<2 * DI, DM, 32, 96><<<dim3(6, M / 32), 256, 0, stream>>>(x, in_proj_w, xz, M);
  // 2. depthwise conv + SiLU -> xc (B,L,D)
  conv_silu<<<(BATCH * LSEQ * DI) / 256, 256, 0, stream>>>(xz, conv_w, conv_b, xc);
  // 3. x_proj for all directions, position space: xdbl[M,160]
  gemm_rt<XDS, DI, 32, 96><<<dim3(3, M / 32), 256, 0, stream>>>(xc, Wcat, xdbl, M);
  // 4. dt projection + softplus -> delta[bp][k][d]
  dt_softplus<<<dim3(M / 16, 3), 256, 0, stream>>>(xdbl, dt_w, dt_b, delta);
  // 5. scan phase 1
  scan_phase1<<<dim3(NCH, KD, BATCH), 192, 0, stream>>>(delta, xc, xdbl, A_logs, hN, sumd);
  // 6. chunk combine (in-place: hN -> entry states)
  chunk_combine<<<(BATCH * KD * DI * NS) / 256, 256, 0, stream>>>(hN, sumd, A_logs);
  // 7. scan phase 2 -> yg (merged over directions)
  hipMemsetAsync(yg, 0, SZ_XC * sizeof(float), stream);
  scan_phase2<<<dim3(NCH, KD, BATCH), 192, 0, stream>>>(delta, xc, xdbl, A_logs, hN, yg);
  // 8. merge + LN + gate -> ymul (reuses delta buffer)
  fuse_ln<<<M, DI, 0, stream>>>(yg, xc, Ds, xz, ln_w, ln_b, ymul);
  // 9. out_proj: out[M,96] = ymul[M,192] @ out_proj_w[96,192]^T
  gemm_rt<DM, DI, 16, 96><<<dim3(2, M / 16), 256, 0, stream>>>(ymul, out_proj_w, out, M);
}

// Round 3
// 338.090 us; speedup vs baseline: 2.2683x; 2.2683x over previous
//
#include <hip/hip_runtime.h>

// ---------------- problem constants ----------------
constexpr int BATCH = 4;
constexpr int HS    = 64;     // H
constexpr int WSZ   = 64;     // W
constexpr int LSEQ  = 4096;   // L = H*W
constexpr int DM    = 96;     // d_model
constexpr int DI    = 192;    // d_inner
constexpr int NS    = 16;     // d_state
constexpr int RK    = 6;      // dt_rank
constexpr int KD    = 4;      // scan directions
constexpr int NCH   = 64;     // chunks along L
constexpr int CLEN  = 64;     // chunk length
constexpr int XDS   = 160;    // packed xdbl row: 4 * [B(16) C(16) dt(6) pad(2)]

// scan index l -> spatial position p (row-major h*64+w), per direction
__device__ __forceinline__ int pos_of(int k, int l) {
  switch (k & 3) {
    case 0: return l;
    case 1: return ((l & 63) << 6) | (l >> 6);          // l = w*H+h -> p = h*W+w
    case 2: return LSEQ - 1 - l;
    default: { int lp = LSEQ - 1 - l; return ((lp & 63) << 6) | (lp >> 6); }
  }
}

// ---------------- generic small-K GEMM: C[M,NN] = A[M,KK] * Bw[NN,KK]^T ----------------
template <int NN, int KK, int TM, int KT>
__launch_bounds__(256)
__global__ void gemm_rt(const float* __restrict__ A, const float* __restrict__ Bw,
                        float* __restrict__ C, int M) {
  constexpr int TN  = 64;
  constexpr int RPT = TM / 16;          // rows per thread
  constexpr int SA  = TM + 2;           // padded stride
  constexpr int KQ  = KT / 4;
  __shared__ float AsT[KT][SA];
  __shared__ float BsT[KT][TN];
  const int t = threadIdx.x;
  const int row0 = blockIdx.y * TM;
  const int col0 = blockIdx.x * TN;
  const int tc = t & 15;        // 16 col groups * 4 cols
  const int tr = t >> 4;        // 16 row groups * RPT rows

  float acc[RPT][4];
  #pragma unroll
  for (int i = 0; i < RPT; ++i)
    { acc[i][0]=0.f; acc[i][1]=0.f; acc[i][2]=0.f; acc[i][3]=0.f; }

  for (int k0 = 0; k0 < KK; k0 += KT) {
    #pragma unroll 1
    for (int idx = t; idx < TM * KQ; idx += 256) {
      int r = idx / KQ, kq = idx % KQ;
      float4 v = *(const float4*)&A[(size_t)(row0 + r) * KK + k0 + kq * 4];
      AsT[kq*4+0][r] = v.x; AsT[kq*4+1][r] = v.y;
      AsT[kq*4+2][r] = v.z; AsT[kq*4+3][r] = v.w;
    }
    #pragma unroll 1
    for (int idx = t; idx < TN * KQ; idx += 256) {
      int c = idx / KQ, kq = idx % KQ;
      int col = col0 + c;
      float4 v = make_float4(0.f, 0.f, 0.f, 0.f);
      if (col < NN) v = *(const float4*)&Bw[(size_t)col * KK + k0 + kq * 4];
      BsT[kq*4+0][c] = v.x; BsT[kq*4+1][c] = v.y;
      BsT[kq*4+2][c] = v.z; BsT[kq*4+3][c] = v.w;
    }
    __syncthreads();
    #pragma unroll 4
    for (int kk = 0; kk < KT; ++kk) {
      float4 bv = *(const float4*)&BsT[kk][tc * 4];
      #pragma unroll
      for (int i = 0; i < RPT; ++i) {
        float a = AsT[kk][tr * RPT + i];
        acc[i][0] += a * bv.x; acc[i][1] += a * bv.y;
        acc[i][2] += a * bv.z; acc[i][3] += a * bv.w;
      }
    }
    __syncthreads();
  }
  int c = col0 + tc * 4;
  if (c < NN) {
    #pragma unroll
    for (int i = 0; i < RPT; ++i) {
      size_t r0 = (size_t)(row0 + tr * RPT + i) * NN + c;
      *(float4*)&C[r0] = make_float4(acc[i][0], acc[i][1], acc[i][2], acc[i][3]);
    }
  }
}

// ---------------- depthwise 3x3 conv + bias + SiLU ----------------
__launch_bounds__(256)
__global__ void conv_silu(const float* __restrict__ xz, const float* __restrict__ cw,
                          const float* __restrict__ cb, float* __restrict__ xc) {
  int idx = blockIdx.x * 256 + threadIdx.x;     // over B*L*DI, grid exact
  int d = idx % DI;
  int p = (idx / DI) % LSEQ;
  int b = idx / (DI * LSEQ);
  int h = p >> 6, w = p & 63;
  float acc = cb[d];
  #pragma unroll
  for (int kh = 0; kh < 3; ++kh) {
    int hh = h + kh - 1;
    if ((unsigned)hh >= (unsigned)HS) continue;
    #pragma unroll
    for (int kw = 0; kw < 3; ++kw) {
      int ww = w + kw - 1;
      if ((unsigned)ww >= (unsigned)WSZ) continue;
      acc += xz[((size_t)b * LSEQ + (hh << 6) + ww) * (2 * DI) + d] * cw[d * 9 + kh * 3 + kw];
    }
  }
  xc[idx] = acc / (1.f + __expf(-acc));   // SiLU
}

// ---------------- build packed weight matrix Wcat[160][192] ----------------
__launch_bounds__(256)
__global__ void build_wcat(const float* __restrict__ xw, float* __restrict__ Wcat) {
  int idx = blockIdx.x * 256 + threadIdx.x;   // < 160*192, grid exact
  int j = idx / DI, col = idx % DI;
  int k = j / 40, jj = j % 40;
  float v = 0.f;
  int src = -1;
  if (jj < 16)      src = k * 38 + 6 + jj;
  else if (jj < 32) src = k * 38 + 22 + (jj - 16);
  else if (jj < 38) src = k * 38 + (jj - 32);
  if (src >= 0) v = xw[(size_t)src * DI + col];
  Wcat[idx] = v;
}

// ---------------- dt rank-6 projection + softplus -> delta[bp][k][d] ----------------
__launch_bounds__(256)
__global__ void dt_softplus(const float* __restrict__ xdbl, const float* __restrict__ dtw,
                            const float* __restrict__ dtb, float* __restrict__ delta) {
  const int t = threadIdx.x;
  const int g = blockIdx.y * 256 + t;    // 0..767 over (k,d)
  const int d = g % DI;
  const int k = g / DI;
  float w[RK];
  #pragma unroll
  for (int r = 0; r < RK; ++r) w[r] = dtw[((size_t)k * DI + d) * RK + r];
  const float bsv = dtb[k * DI + d];
  const int p0 = blockIdx.x * 16;
  #pragma unroll 1
  for (int j = 0; j < 16; ++j) {
    const size_t bp = p0 + j;
    const float* xr = &xdbl[bp * XDS + k * 40 + 32];
    float s = bsv;
    #pragma unroll
    for (int r = 0; r < RK; ++r) s += w[r] * xr[r];
    float dv = (s > 20.f) ? s : log1pf(__expf(s));
    delta[(bp * KD + k) * DI + d] = dv;
  }
}

// ---------------- scan phase 1: per-chunk local states + sum(delta) ----------------
__launch_bounds__(192)
__global__ void scan_phase1(const float* __restrict__ delta, const float* __restrict__ xc,
                            const float* __restrict__ xdbl, const float* __restrict__ Alog,
                            float* __restrict__ hN, float* __restrict__ sumdB) {
  const int d = threadIdx.x;
  const int ch = blockIdx.x, k = blockIdx.y, b = blockIdx.z;
  const int bk = b * KD + k;
  __shared__ float4 Bsh[CLEN * 4];
  #pragma unroll 1
  for (int idx = d; idx < CLEN * 4; idx += 192) {
    int j = idx >> 2, q = idx & 3;
    int p = pos_of(k, ch * CLEN + j);
    Bsh[idx] = *(const float4*)&xdbl[(size_t)(b * LSEQ + p) * XDS + k * 40 + q * 4];
  }
  float An[NS];
  {
    const float4* Ap = (const float4*)&Alog[((size_t)k * DI + d) * NS];
    #pragma unroll
    for (int q = 0; q < 4; ++q) {
      float4 a = Ap[q];
      An[q*4+0] = -__expf(a.x); An[q*4+1] = -__expf(a.y);
      An[q*4+2] = -__expf(a.z); An[q*4+3] = -__expf(a.w);
    }
  }
  const float An0 = An[0];
  bool geo = true;
  #pragma unroll
  for (int n = 0; n < NS; ++n)
    geo = geo && (fabsf(An[n] - (n + 1) * An0) <= 1e-3f * fabsf(An[n]));
  __syncthreads();

  float h[NS];
  #pragma unroll
  for (int n = 0; n < NS; ++n) h[n] = 0.f;
  float sumd = 0.f;
  const int l0 = ch * CLEN;
  if (geo) {
    #pragma unroll 2
    for (int j = 0; j < CLEN; ++j) {
      const int p = pos_of(k, l0 + j);
      const size_t bp = (size_t)b * LSEQ + p;
      float dl = delta[(bp * KD + k) * DI + d];
      float du = dl * xc[bp * DI + d];
      float w = __expf(dl * An0), wp = 1.f;
      #pragma unroll
      for (int q = 0; q < 4; ++q) {
        float4 v = Bsh[j * 4 + q];
        wp *= w; h[q*4+0] = wp * h[q*4+0] + du * v.x;
        wp *= w; h[q*4+1] = wp * h[q*4+1] + du * v.y;
        wp *= w; h[q*4+2] = wp * h[q*4+2] + du * v.z;
        wp *= w; h[q*4+3] = wp * h[q*4+3] + du * v.w;
      }
      sumd += dl;
    }
  } else {
    #pragma unroll 1
    for (int j = 0; j < CLEN; ++j) {
      const int p = pos_of(k, l0 + j);
      const size_t bp = (size_t)b * LSEQ + p;
      float dl = delta[(bp * KD + k) * DI + d];
      float du = dl * xc[bp * DI + d];
      #pragma unroll
      for (int q = 0; q < 4; ++q) {
        float4 v = Bsh[j * 4 + q];
        h[q*4+0] = __expf(dl * An[q*4+0]) * h[q*4+0] + du * v.x;
        h[q*4+1] = __expf(dl * An[q*4+1]) * h[q*4+1] + du * v.y;
        h[q*4+2] = __expf(dl * An[q*4+2]) * h[q*4+2] + du * v.z;
        h[q*4+3] = __expf(dl * An[q*4+3]) * h[q*4+3] + du * v.w;
      }
      sumd += dl;
    }
  }
  const size_t o = ((size_t)bk * NCH + ch) * DI + d;
  float4* Hp = (float4*)&hN[o * NS];
  #pragma unroll
  for (int q = 0; q < 4; ++q)
    Hp[q] = make_float4(h[q*4+0], h[q*4+1], h[q*4+2], h[q*4+3]);
  sumdB[o] = sumd;
}

// ---------------- sequential chunk combine (in-place: hN becomes entry states) ----------------
__launch_bounds__(256)
__global__ void chunk_combine(float* __restrict__ hN, const float* __restrict__ sumdB,
                              const float* __restrict__ Alog) {
  const int tid = blockIdx.x * 256 + threadIdx.x;   // over B*K*D*N
  const int n  = tid & 15;
  const int dd = tid >> 4;
  const int d  = dd % DI;
  const int bk = dd / DI;
  const int k  = bk & 3;
  const float An = -__expf(Alog[((size_t)k * DI + d) * NS + n]);
  float h = 0.f;
  #pragma unroll 1
  for (int c = 0; c < NCH; ++c) {
    const size_t o = ((size_t)bk * NCH + c) * DI + d;
    float tmp = hN[o * NS + n];
    hN[o * NS + n] = h;
    h = tmp + __expf(An * sumdB[o]) * h;
  }
}

// ---------------- scan phase 2: entry state, emit y (merged via atomics) ----------------
__launch_bounds__(192)
__global__ void scan_phase2(const float* __restrict__ delta, const float* __restrict__ xc,
                            const float* __restrict__ xdbl, const float* __restrict__ Alog,
                            const float* __restrict__ hin, float* __restrict__ yg) {
  const int d = threadIdx.x;
  const int ch = blockIdx.x, k = blockIdx.y, b = blockIdx.z;
  const int bk = b * KD + k;
  __shared__ float4 Bsh[CLEN * 8];
  #pragma unroll 1
  for (int idx = d; idx < CLEN * 8; idx += 192) {
    int j = idx >> 3, q = idx & 7;
    int p = pos_of(k, ch * CLEN + j);
    Bsh[idx] = *(const float4*)&xdbl[(size_t)(b * LSEQ + p) * XDS + k * 40 + q * 4];
  }
  float An[NS];
  {
    const float4* Ap = (const float4*)&Alog[((size_t)k * DI + d) * NS];
    #pragma unroll
    for (int q = 0; q < 4; ++q) {
      float4 a = Ap[q];
      An[q*4+0] = -__expf(a.x); An[q*4+1] = -__expf(a.y);
      An[q*4+2] = -__expf(a.z); An[q*4+3] = -__expf(a.w);
    }
  }
  const float An0 = An[0];
  bool geo = true;
  #pragma unroll
  for (int n = 0; n < NS; ++n)
    geo = geo && (fabsf(An[n] - (n + 1) * An0) <= 1e-3f * fabsf(An[n]));

  float h[NS];
  {
    const size_t o = ((size_t)bk * NCH + ch) * DI + d;
    const float4* Hp = (const float4*)&hin[o * NS];
    #pragma unroll
    for (int q = 0; q < 4; ++q) {
      float4 v = Hp[q];
      h[q*4+0] = v.x; h[q*4+1] = v.y; h[q*4+2] = v.z; h[q*4+3] = v.w;
    }
  }
  __syncthreads();
  const int l0 = ch * CLEN;
  if (geo) {
    #pragma unroll 2
    for (int j = 0; j < CLEN; ++j) {
      const int p = pos_of(k, l0 + j);
      const size_t bp = (size_t)b * LSEQ + p;
      float dl = delta[(bp * KD + k) * DI + d];
      float du = dl * xc[bp * DI + d];
      float w = __expf(dl * An0), wp = 1.f;
      float y = 0.f;
      #pragma unroll
      for (int q = 0; q < 4; ++q) {
        float4 v  = Bsh[j * 8 + q];
        float4 c4 = Bsh[j * 8 + 4 + q];
        wp *= w; h[q*4+0] = wp * h[q*4+0] + du * v.x; y += h[q*4+0] * c4.x;
        wp *= w; h[q*4+1] = wp * h[q*4+1] + du * v.y; y += h[q*4+1] * c4.y;
        wp *= w; h[q*4+2] = wp * h[q*4+2] + du * v.z; y += h[q*4+2] * c4.z;
        wp *= w; h[q*4+3] = wp * h[q*4+3] + du * v.w; y += h[q*4+3] * c4.w;
      }
      atomicAdd(&yg[bp * DI + d], y);
    }
  } else {
    #pragma unroll 1
    for (int j = 0; j < CLEN; ++j) {
      const int p = pos_of(k, l0 + j);
      const size_t bp = (size_t)b * LSEQ + p;
      float dl = delta[(bp * KD + k) * DI + d];
      float du = dl * xc[bp * DI + d];
      float y = 0.f;
      #pragma unroll
      for (int q = 0; q < 4; ++q) {
        float4 v  = Bsh[j * 8 + q];
        float4 c4 = Bsh[j * 8 + 4 + q];
        h[q*4+0] = __expf(dl * An[q*4+0]) * h[q*4+0] + du * v.x; y += h[q*4+0] * c4.x;
        h[q*4+1] = __expf(dl * An[q*4+1]) * h[q*4+1] + du * v.y; y += h[q*4+1] * c4.y;
        h[q*4+2] = __expf(dl * An[q*4+2]) * h[q*4+2] + du * v.z; y += h[q*4+2] * c4.z;
        h[q*4+3] = __expf(dl * An[q*4+3]) * h[q*4+3] + du * v.w; y += h[q*4+3] * c4.w;
      }
      atomicAdd(&yg[bp * DI + d], y);
    }
  }
}

// ---------------- direction merge (Ds term) + LayerNorm + SiLU gate ----------------
__launch_bounds__(192)
__global__ void fuse_ln(const float* __restrict__ yg, const float* __restrict__ xc,
                        const float* __restrict__ Ds, const float* __restrict__ xz,
                        const float* __restrict__ lnw, const float* __restrict__ lnb,
                        float* __restrict__ ymul) {
  const int row = blockIdx.x;        // b*L + p
  const int d = threadIdx.x;
  float u = xc[(size_t)row * DI + d];
  float sDs = Ds[d] + Ds[DI + d] + Ds[2 * DI + d] + Ds[3 * DI + d];
  float y = yg[(size_t)row * DI + d] + sDs * u;
  float s1 = y, s2 = y * y;
  #pragma unroll
  for (int off = 32; off; off >>= 1) {
    s1 += __shfl_xor(s1, off);
    s2 += __shfl_xor(s2, off);
  }
  __shared__ float r1[3], r2[3];
  int wid = d >> 6;
  if ((d & 63) == 0) { r1[wid] = s1; r2[wid] = s2; }
  __syncthreads();
  float S1 = r1[0] + r1[1] + r1[2];
  float S2 = r2[0] + r2[1] + r2[2];
  float mu = S1 * (1.f / DI);
  float var = S2 * (1.f / DI) - mu * mu;
  float yn = (y - mu) * rsqrtf(var + 1e-5f) * lnw[d] + lnb[d];
  float zv = xz[(size_t)row * (2 * DI) + DI + d];
  float g = zv / (1.f + __expf(-zv));
  ymul[(size_t)row * DI + d] = yn * g;
}

// ---------------- launcher ----------------
extern "C" void kernel_launch(void* const* d_in, const int* in_sizes, int n_in,
                              void* d_out, int out_size, void* d_ws, size_t ws_size,
                              hipStream_t stream) {
  (void)in_sizes; (void)n_in; (void)out_size; (void)ws_size;
  const float* x          = (const float*)d_in[0];
  const float* in_proj_w  = (const float*)d_in[1];
  const float* conv_w     = (const float*)d_in[2];
  const float* conv_b     = (const float*)d_in[3];
  const float* x_proj_w   = (const float*)d_in[4];
  const float* dt_w       = (const float*)d_in[5];
  const float* dt_b       = (const float*)d_in[6];
  const float* A_logs     = (const float*)d_in[7];
  const float* Ds         = (const float*)d_in[8];
  const float* ln_w       = (const float*)d_in[9];
  const float* ln_b       = (const float*)d_in[10];
  const float* out_proj_w = (const float*)d_in[11];
  float* out = (float*)d_out;
  float* ws  = (float*)d_ws;

  constexpr size_t SZ_XZ    = (size_t)BATCH * LSEQ * 2 * DI;
  constexpr size_t SZ_XC    = (size_t)BATCH * LSEQ * DI;
  constexpr size_t SZ_XD    = (size_t)BATCH * LSEQ * XDS;
  constexpr size_t SZ_DELTA = (size_t)BATCH * KD * LSEQ * DI;
  constexpr size_t SZ_HN    = (size_t)BATCH * KD * NCH * DI * NS;
  constexpr size_t SZ_SUMD  = (size_t)BATCH * KD * NCH * DI;

  float* xz    = ws;
  float* xc    = xz + SZ_XZ;
  float* xdbl  = xc + SZ_XC;
  float* delta = xdbl + SZ_XD;
  float* hN    = delta + SZ_DELTA;
  float* sumd  = hN + SZ_HN;
  float* yg    = sumd + SZ_SUMD;
  float* Wcat  = yg + SZ_XC;
  float* ymul  = delta;   // delta dead after scan_phase2

  const int M = BATCH * LSEQ;  // 16384

  // 0. pack x_proj weights for all 4 directions
  build_wcat<<<(XDS * DI) / 256, 256, 0, stream>>>(x_proj_w, Wcat);
  // 1. in_proj: xz[M,384] = x[M,96] @ in_proj_w[384,96]^T
  gemm_rt<2 * DI, DM, 32, 96><<<dim3(6, M / 32), 256, 0, stream>>>(x, in_proj_w, xz, M);
  // 2. depthwise conv + SiLU -> xc (B,L,D)
  conv_silu<<<(BATCH * LSEQ * DI) / 256, 256, 0, stream>>>(xz, conv_w, conv_b, xc);
  // 3. x_proj for all directions, position space: xdbl[M,160]
  gemm_rt<XDS, DI, 32, 96><<<dim3(3, M / 32), 256, 0, stream>>>(xc, Wcat, xdbl, M);
  // 4. dt projection + softplus -> delta[bp][k][d]
  dt_softplus<<<dim3(M / 16, 3), 256, 0, stream>>>(xdbl, dt_w, dt_b, delta);
  // 5. scan phase 1
  scan_phase1<<<dim3(NCH, KD, BATCH), 192, 0, stream>>>(delta, xc, xdbl, A_logs, hN, sumd);
  // 6. chunk combine (in-place: hN -> entry states)
  chunk_combine<<<(BATCH * KD * DI * NS) / 256, 256, 0, stream>>>(hN, sumd, A_logs);
  // 7. scan phase 2 -> yg (merged over directions)
  hipMemsetAsync(yg, 0, SZ_XC * sizeof(float), stream);
  scan_phase2<<<dim3(NCH, KD, BATCH), 192, 0, stream>>>(delta, xc, xdbl, A_logs, hN, yg);
  // 8. merge + LN + gate -> ymul (reuses delta buffer)
  fuse_ln<<<M, DI, 0, stream>>>(yg, xc, Ds, xz, ln_w, ln_b, ymul);
  // 9. out_proj: out[M,96] = ymul[M,192] @ out_proj_w[96,192]^T
  gemm_rt<DM, DI, 16, 96><<<dim3(2, M / 16), 256, 0, stream>>>(ymul, out_proj_w, out, M);
}

// Round 4
// 268.790 us; speedup vs baseline: 2.8531x; 1.2578x over previous
//
#include <hip/hip_runtime.h>

// ---------------- problem constants ----------------
constexpr int BATCH = 4;
constexpr int HS    = 64;     // H
constexpr int WSZ   = 64;     // W
constexpr int LSEQ  = 4096;   // L = H*W
constexpr int DM    = 96;     // d_model
constexpr int DI    = 192;    // d_inner
constexpr int NS    = 16;     // d_state
constexpr int RK    = 6;      // dt_rank
constexpr int KD    = 4;      // scan directions
constexpr int NCH   = 64;     // chunks along L
constexpr int CLEN  = 64;     // chunk length
constexpr int XDS   = 160;    // packed xdbl row: 4 * [B(16) C(16) dt(6) pad(2)]

// scan index l -> spatial position p (row-major h*64+w), per direction
__device__ __forceinline__ int pos_of(int k, int l) {
  switch (k & 3) {
    case 0: return l;
    case 1: return ((l & 63) << 6) | (l >> 6);          // l = w*H+h -> p = h*W+w
    case 2: return LSEQ - 1 - l;
    default: { int lp = LSEQ - 1 - l; return ((lp & 63) << 6) | (lp >> 6); }
  }
}

// ---------------- weight transpose: out[c][r] = in[r][c] ----------------
__launch_bounds__(256)
__global__ void transpose_w(const float* __restrict__ in, float* __restrict__ outp,
                            int R, int C_) {
  int idx = blockIdx.x * 256 + threadIdx.x;
  if (idx < R * C_) {
    int r = idx / C_, c = idx % C_;      // coalesced read
    outp[(size_t)c * R + r] = in[idx];   // scattered write (tiny matrix, L2)
  }
}

// ---------------- GEMM: C[M,NN] = A[M,KK] * BT[KK,NN]   (BT pre-transposed) ------
// A staged natural-layout with +4 pad (conflict-free scalar col reads);
// B staged as straight row copy (conflict-free).
template <int NN, int KK, int TM, int KT>
__launch_bounds__(256)
__global__ void gemm_nt(const float* __restrict__ A, const float* __restrict__ BT,
                        float* __restrict__ C, int M) {
  constexpr int TN  = 64;
  constexpr int RPT = TM / 16;          // rows per thread
  constexpr int SA  = KT + 4;           // padded row stride (words)
  constexpr int KQ  = KT / 4;
  __shared__ float As[TM][SA];
  __shared__ float Bs[KT][TN];
  const int t = threadIdx.x;
  const int row0 = blockIdx.y * TM;
  const int col0 = blockIdx.x * TN;
  const int tc = t & 15;        // 16 col groups * 4 cols
  const int tr = t >> 4;        // 16 row groups * RPT rows

  float acc[RPT][4];
  #pragma unroll
  for (int i = 0; i < RPT; ++i)
    { acc[i][0]=0.f; acc[i][1]=0.f; acc[i][2]=0.f; acc[i][3]=0.f; }

  for (int k0 = 0; k0 < KK; k0 += KT) {
    #pragma unroll 1
    for (int idx = t; idx < TM * KQ; idx += 256) {
      int r = idx / KQ, kq = idx % KQ;
      *(float4*)&As[r][kq * 4] =
          *(const float4*)&A[(size_t)(row0 + r) * KK + k0 + kq * 4];
    }
    #pragma unroll 1
    for (int idx = t; idx < KT * 16; idx += 256) {
      int kk = idx >> 4, cq = idx & 15;
      int col = col0 + cq * 4;
      float4 v = make_float4(0.f, 0.f, 0.f, 0.f);
      if (col < NN) v = *(const float4*)&BT[(size_t)(k0 + kk) * NN + col];
      *(float4*)&Bs[kk][cq * 4] = v;
    }
    __syncthreads();
    #pragma unroll 4
    for (int kk = 0; kk < KT; ++kk) {
      float4 bv = *(const float4*)&Bs[kk][tc * 4];
      #pragma unroll
      for (int i = 0; i < RPT; ++i) {
        float a = As[tr * RPT + i][kk];
        acc[i][0] += a * bv.x; acc[i][1] += a * bv.y;
        acc[i][2] += a * bv.z; acc[i][3] += a * bv.w;
      }
    }
    __syncthreads();
  }
  int c = col0 + tc * 4;
  if (c < NN) {
    #pragma unroll
    for (int i = 0; i < RPT; ++i) {
      size_t r0 = (size_t)(row0 + tr * RPT + i) * NN + c;
      *(float4*)&C[r0] = make_float4(acc[i][0], acc[i][1], acc[i][2], acc[i][3]);
    }
  }
}

// ---------------- depthwise 3x3 conv + bias + SiLU ----------------
__launch_bounds__(256)
__global__ void conv_silu(const float* __restrict__ xz, const float* __restrict__ cw,
                          const float* __restrict__ cb, float* __restrict__ xc) {
  int idx = blockIdx.x * 256 + threadIdx.x;     // over B*L*DI, grid exact
  int d = idx % DI;
  int p = (idx / DI) % LSEQ;
  int b = idx / (DI * LSEQ);
  int h = p >> 6, w = p & 63;
  float acc = cb[d];
  #pragma unroll
  for (int kh = 0; kh < 3; ++kh) {
    int hh = h + kh - 1;
    if ((unsigned)hh >= (unsigned)HS) continue;
    #pragma unroll
    for (int kw = 0; kw < 3; ++kw) {
      int ww = w + kw - 1;
      if ((unsigned)ww >= (unsigned)WSZ) continue;
      acc += xz[((size_t)b * LSEQ + (hh << 6) + ww) * (2 * DI) + d] * cw[d * 9 + kh * 3 + kw];
    }
  }
  xc[idx] = acc / (1.f + __expf(-acc));   // SiLU
}

// ---------------- build packed+transposed weight WcatT[192][160] ----------------
// WcatT[col][j] with j = k*40+jj: jj<16 -> Bs row; jj<32 -> Cs row; jj<38 -> dt row
__launch_bounds__(256)
__global__ void build_wcatT(const float* __restrict__ xw, float* __restrict__ WcatT) {
  int idx = blockIdx.x * 256 + threadIdx.x;   // < 192*160, grid exact
  int col = idx / XDS, j = idx % XDS;
  int k = j / 40, jj = j % 40;
  float v = 0.f;
  int src = -1;
  if (jj < 16)      src = k * 38 + 6 + jj;
  else if (jj < 32) src = k * 38 + 22 + (jj - 16);
  else if (jj < 38) src = k * 38 + (jj - 32);
  if (src >= 0) v = xw[(size_t)src * DI + col];
  WcatT[idx] = v;
}

// ---------------- dt rank-6 projection + softplus -> delta[bp][k][d] ----------------
__launch_bounds__(256)
__global__ void dt_softplus(const float* __restrict__ xdbl, const float* __restrict__ dtw,
                            const float* __restrict__ dtb, float* __restrict__ delta) {
  const int t = threadIdx.x;
  const int g = blockIdx.y * 256 + t;    // 0..767 over (k,d)
  const int d = g % DI;
  const int k = g / DI;
  float w[RK];
  #pragma unroll
  for (int r = 0; r < RK; ++r) w[r] = dtw[((size_t)k * DI + d) * RK + r];
  const float bsv = dtb[k * DI + d];
  const int p0 = blockIdx.x * 16;
  #pragma unroll 1
  for (int j = 0; j < 16; ++j) {
    const size_t bp = p0 + j;
    const float* xr = &xdbl[bp * XDS + k * 40 + 32];
    float s = bsv;
    #pragma unroll
    for (int r = 0; r < RK; ++r) s += w[r] * xr[r];
    float dv = (s > 20.f) ? s : log1pf(__expf(s));
    delta[(bp * KD + k) * DI + d] = dv;
  }
}

// ---------------- scan phase 1: per-chunk local states + sum(delta) ----------------
__launch_bounds__(192)
__global__ void scan_phase1(const float* __restrict__ delta, const float* __restrict__ xc,
                            const float* __restrict__ xdbl, const float* __restrict__ Alog,
                            float* __restrict__ hN, float* __restrict__ sumdB) {
  const int d = threadIdx.x;
  const int ch = blockIdx.x, k = blockIdx.y, b = blockIdx.z;
  const int bk = b * KD + k;
  __shared__ float4 Bsh[CLEN * 4];
  #pragma unroll 1
  for (int idx = d; idx < CLEN * 4; idx += 192) {
    int j = idx >> 2, q = idx & 3;
    int p = pos_of(k, ch * CLEN + j);
    Bsh[idx] = *(const float4*)&xdbl[(size_t)(b * LSEQ + p) * XDS + k * 40 + q * 4];
  }
  float An[NS];
  {
    const float4* Ap = (const float4*)&Alog[((size_t)k * DI + d) * NS];
    #pragma unroll
    for (int q = 0; q < 4; ++q) {
      float4 a = Ap[q];
      An[q*4+0] = -__expf(a.x); An[q*4+1] = -__expf(a.y);
      An[q*4+2] = -__expf(a.z); An[q*4+3] = -__expf(a.w);
    }
  }
  const float An0 = An[0];
  bool geo = true;
  #pragma unroll
  for (int n = 0; n < NS; ++n)
    geo = geo && (fabsf(An[n] - (n + 1) * An0) <= 1e-3f * fabsf(An[n]));
  __syncthreads();

  float h[NS];
  #pragma unroll
  for (int n = 0; n < NS; ++n) h[n] = 0.f;
  float sumd = 0.f;
  const int l0 = ch * CLEN;
  if (geo) {
    #pragma unroll 2
    for (int j = 0; j < CLEN; ++j) {
      const int p = pos_of(k, l0 + j);
      const size_t bp = (size_t)b * LSEQ + p;
      float dl = delta[(bp * KD + k) * DI + d];
      float du = dl * xc[bp * DI + d];
      float w = __expf(dl * An0), wp = 1.f;
      #pragma unroll
      for (int q = 0; q < 4; ++q) {
        float4 v = Bsh[j * 4 + q];
        wp *= w; h[q*4+0] = wp * h[q*4+0] + du * v.x;
        wp *= w; h[q*4+1] = wp * h[q*4+1] + du * v.y;
        wp *= w; h[q*4+2] = wp * h[q*4+2] + du * v.z;
        wp *= w; h[q*4+3] = wp * h[q*4+3] + du * v.w;
      }
      sumd += dl;
    }
  } else {
    #pragma unroll 1
    for (int j = 0; j < CLEN; ++j) {
      const int p = pos_of(k, l0 + j);
      const size_t bp = (size_t)b * LSEQ + p;
      float dl = delta[(bp * KD + k) * DI + d];
      float du = dl * xc[bp * DI + d];
      #pragma unroll
      for (int q = 0; q < 4; ++q) {
        float4 v = Bsh[j * 4 + q];
        h[q*4+0] = __expf(dl * An[q*4+0]) * h[q*4+0] + du * v.x;
        h[q*4+1] = __expf(dl * An[q*4+1]) * h[q*4+1] + du * v.y;
        h[q*4+2] = __expf(dl * An[q*4+2]) * h[q*4+2] + du * v.z;
        h[q*4+3] = __expf(dl * An[q*4+3]) * h[q*4+3] + du * v.w;
      }
      sumd += dl;
    }
  }
  const size_t o = ((size_t)bk * NCH + ch) * DI + d;
  float4* Hp = (float4*)&hN[o * NS];
  #pragma unroll
  for (int q = 0; q < 4; ++q)
    Hp[q] = make_float4(h[q*4+0], h[q*4+1], h[q*4+2], h[q*4+3]);
  sumdB[o] = sumd;
}

// ---------------- sequential chunk combine (in-place: hN becomes entry states) ----------------
__launch_bounds__(256)
__global__ void chunk_combine(float* __restrict__ hN, const float* __restrict__ sumdB,
                              const float* __restrict__ Alog) {
  const int tid = blockIdx.x * 256 + threadIdx.x;   // over B*K*D*N
  const int n  = tid & 15;
  const int dd = tid >> 4;
  const int d  = dd % DI;
  const int bk = dd / DI;
  const int k  = bk & 3;
  const float An = -__expf(Alog[((size_t)k * DI + d) * NS + n]);
  float h = 0.f;
  #pragma unroll 1
  for (int c = 0; c < NCH; ++c) {
    const size_t o = ((size_t)bk * NCH + c) * DI + d;
    float tmp = hN[o * NS + n];
    hN[o * NS + n] = h;
    h = tmp + __expf(An * sumdB[o]) * h;
  }
}

// ---------------- scan phase 2: entry state, emit y (merged via atomics) ----------------
__launch_bounds__(192)
__global__ void scan_phase2(const float* __restrict__ delta, const float* __restrict__ xc,
                            const float* __restrict__ xdbl, const float* __restrict__ Alog,
                            const float* __restrict__ hin, float* __restrict__ yg) {
  const int d = threadIdx.x;
  const int ch = blockIdx.x, k = blockIdx.y, b = blockIdx.z;
  const int bk = b * KD + k;
  __shared__ float4 Bsh[CLEN * 8];
  #pragma unroll 1
  for (int idx = d; idx < CLEN * 8; idx += 192) {
    int j = idx >> 3, q = idx & 7;
    int p = pos_of(k, ch * CLEN + j);
    Bsh[idx] = *(const float4*)&xdbl[(size_t)(b * LSEQ + p) * XDS + k * 40 + q * 4];
  }
  float An[NS];
  {
    const float4* Ap = (const float4*)&Alog[((size_t)k * DI + d) * NS];
    #pragma unroll
    for (int q = 0; q < 4; ++q) {
      float4 a = Ap[q];
      An[q*4+0] = -__expf(a.x); An[q*4+1] = -__expf(a.y);
      An[q*4+2] = -__expf(a.z); An[q*4+3] = -__expf(a.w);
    }
  }
  const float An0 = An[0];
  bool geo = true;
  #pragma unroll
  for (int n = 0; n < NS; ++n)
    geo = geo && (fabsf(An[n] - (n + 1) * An0) <= 1e-3f * fabsf(An[n]));

  float h[NS];
  {
    const size_t o = ((size_t)bk * NCH + ch) * DI + d;
    const float4* Hp = (const float4*)&hin[o * NS];
    #pragma unroll
    for (int q = 0; q < 4; ++q) {
      float4 v = Hp[q];
      h[q*4+0] = v.x; h[q*4+1] = v.y; h[q*4+2] = v.z; h[q*4+3] = v.w;
    }
  }
  __syncthreads();
  const int l0 = ch * CLEN;
  if (geo) {
    #pragma unroll 2
    for (int j = 0; j < CLEN; ++j) {
      const int p = pos_of(k, l0 + j);
      const size_t bp = (size_t)b * LSEQ + p;
      float dl = delta[(bp * KD + k) * DI + d];
      float du = dl * xc[bp * DI + d];
      float w = __expf(dl * An0), wp = 1.f;
      float y = 0.f;
      #pragma unroll
      for (int q = 0; q < 4; ++q) {
        float4 v  = Bsh[j * 8 + q];
        float4 c4 = Bsh[j * 8 + 4 + q];
        wp *= w; h[q*4+0] = wp * h[q*4+0] + du * v.x; y += h[q*4+0] * c4.x;
        wp *= w; h[q*4+1] = wp * h[q*4+1] + du * v.y; y += h[q*4+1] * c4.y;
        wp *= w; h[q*4+2] = wp * h[q*4+2] + du * v.z; y += h[q*4+2] * c4.z;
        wp *= w; h[q*4+3] = wp * h[q*4+3] + du * v.w; y += h[q*4+3] * c4.w;
      }
      atomicAdd(&yg[bp * DI + d], y);
    }
  } else {
    #pragma unroll 1
    for (int j = 0; j < CLEN; ++j) {
      const int p = pos_of(k, l0 + j);
      const size_t bp = (size_t)b * LSEQ + p;
      float dl = delta[(bp * KD + k) * DI + d];
      float du = dl * xc[bp * DI + d];
      float y = 0.f;
      #pragma unroll
      for (int q = 0; q < 4; ++q) {
        float4 v  = Bsh[j * 8 + q];
        float4 c4 = Bsh[j * 8 + 4 + q];
        h[q*4+0] = __expf(dl * An[q*4+0]) * h[q*4+0] + du * v.x; y += h[q*4+0] * c4.x;
        h[q*4+1] = __expf(dl * An[q*4+1]) * h[q*4+1] + du * v.y; y += h[q*4+1] * c4.y;
        h[q*4+2] = __expf(dl * An[q*4+2]) * h[q*4+2] + du * v.z; y += h[q*4+2] * c4.z;
        h[q*4+3] = __expf(dl * An[q*4+3]) * h[q*4+3] + du * v.w; y += h[q*4+3] * c4.w;
      }
      atomicAdd(&yg[bp * DI + d], y);
    }
  }
}

// ---------------- direction merge (Ds term) + LayerNorm + SiLU gate ----------------
__launch_bounds__(192)
__global__ void fuse_ln(const float* __restrict__ yg, const float* __restrict__ xc,
                        const float* __restrict__ Ds, const float* __restrict__ xz,
                        const float* __restrict__ lnw, const float* __restrict__ lnb,
                        float* __restrict__ ymul) {
  const int row = blockIdx.x;        // b*L + p
  const int d = threadIdx.x;
  float u = xc[(size_t)row * DI + d];
  float sDs = Ds[d] + Ds[DI + d] + Ds[2 * DI + d] + Ds[3 * DI + d];
  float y = yg[(size_t)row * DI + d] + sDs * u;
  float s1 = y, s2 = y * y;
  #pragma unroll
  for (int off = 32; off; off >>= 1) {
    s1 += __shfl_xor(s1, off);
    s2 += __shfl_xor(s2, off);
  }
  __shared__ float r1[3], r2[3];
  int wid = d >> 6;
  if ((d & 63) == 0) { r1[wid] = s1; r2[wid] = s2; }
  __syncthreads();
  float S1 = r1[0] + r1[1] + r1[2];
  float S2 = r2[0] + r2[1] + r2[2];
  float mu = S1 * (1.f / DI);
  float var = S2 * (1.f / DI) - mu * mu;
  float yn = (y - mu) * rsqrtf(var + 1e-5f) * lnw[d] + lnb[d];
  float zv = xz[(size_t)row * (2 * DI) + DI + d];
  float g = zv / (1.f + __expf(-zv));
  ymul[(size_t)row * DI + d] = yn * g;
}

// ---------------- launcher ----------------
extern "C" void kernel_launch(void* const* d_in, const int* in_sizes, int n_in,
                              void* d_out, int out_size, void* d_ws, size_t ws_size,
                              hipStream_t stream) {
  (void)in_sizes; (void)n_in; (void)out_size; (void)ws_size;
  const float* x          = (const float*)d_in[0];
  const float* in_proj_w  = (const float*)d_in[1];
  const float* conv_w     = (const float*)d_in[2];
  const float* conv_b     = (const float*)d_in[3];
  const float* x_proj_w   = (const float*)d_in[4];
  const float* dt_w       = (const float*)d_in[5];
  const float* dt_b       = (const float*)d_in[6];
  const float* A_logs     = (const float*)d_in[7];
  const float* Ds         = (const float*)d_in[8];
  const float* ln_w       = (const float*)d_in[9];
  const float* ln_b       = (const float*)d_in[10];
  const float* out_proj_w = (const float*)d_in[11];
  float* out = (float*)d_out;
  float* ws  = (float*)d_ws;

  constexpr size_t SZ_XZ    = (size_t)BATCH * LSEQ * 2 * DI;
  constexpr size_t SZ_XC    = (size_t)BATCH * LSEQ * DI;
  constexpr size_t SZ_XD    = (size_t)BATCH * LSEQ * XDS;
  constexpr size_t SZ_DELTA = (size_t)BATCH * KD * LSEQ * DI;
  constexpr size_t SZ_HN    = (size_t)BATCH * KD * NCH * DI * NS;
  constexpr size_t SZ_SUMD  = (size_t)BATCH * KD * NCH * DI;

  float* xz    = ws;
  float* xc    = xz + SZ_XZ;
  float* xdbl  = xc + SZ_XC;
  float* delta = xdbl + SZ_XD;
  float* hN    = delta + SZ_DELTA;
  float* sumd  = hN + SZ_HN;
  float* yg    = sumd + SZ_SUMD;
  float* WcatT = yg + SZ_XC;                    // [192][160]
  float* inpT  = WcatT + (size_t)DI * XDS;      // [96][384]
  float* outpT = inpT + (size_t)DM * 2 * DI;    // [192][96]
  float* ymul  = delta;   // delta dead after scan_phase2

  const int M = BATCH * LSEQ;  // 16384

  // 0. weight prep (transposes + packed Wcat^T)
  build_wcatT<<<(DI * XDS) / 256, 256, 0, stream>>>(x_proj_w, WcatT);
  transpose_w<<<(2 * DI * DM + 255) / 256, 256, 0, stream>>>(in_proj_w, inpT, 2 * DI, DM);
  transpose_w<<<(DM * DI + 255) / 256, 256, 0, stream>>>(out_proj_w, outpT, DM, DI);
  // 1. in_proj: xz[M,384] = x[M,96] @ inpT[96,384]
  gemm_nt<2 * DI, DM, 64, 96><<<dim3(6, M / 64), 256, 0, stream>>>(x, inpT, xz, M);
  // 2. depthwise conv + SiLU -> xc (B,L,D)
  conv_silu<<<(BATCH * LSEQ * DI) / 256, 256, 0, stream>>>(xz, conv_w, conv_b, xc);
  // 3. x_proj all directions, position space: xdbl[M,160] = xc[M,192] @ WcatT[192,160]
  gemm_nt<XDS, DI, 64, 96><<<dim3(3, M / 64), 256, 0, stream>>>(xc, WcatT, xdbl, M);
  // 4. dt projection + softplus -> delta[bp][k][d]
  dt_softplus<<<dim3(M / 16, 3), 256, 0, stream>>>(xdbl, dt_w, dt_b, delta);
  // 5. scan phase 1
  scan_phase1<<<dim3(NCH, KD, BATCH), 192, 0, stream>>>(delta, xc, xdbl, A_logs, hN, sumd);
  // 6. chunk combine (in-place: hN -> entry states)
  chunk_combine<<<(BATCH * KD * DI * NS) / 256, 256, 0, stream>>>(hN, sumd, A_logs);
  // 7. scan phase 2 -> yg (merged over directions)
  hipMemsetAsync(yg, 0, SZ_XC * sizeof(float), stream);
  scan_phase2<<<dim3(NCH, KD, BATCH), 192, 0, stream>>>(delta, xc, xdbl, A_logs, hN, yg);
  // 8. merge + LN + gate -> ymul (reuses delta buffer)
  fuse_ln<<<M, DI, 0, stream>>>(yg, xc, Ds, xz, ln_w, ln_b, ymul);
  // 9. out_proj: out[M,96] = ymul[M,192] @ outpT[192,96]
  gemm_nt<DM, DI, 64, 96><<<dim3(2, M / 64), 256, 0, stream>>>(ymul, outpT, out, M);
}

// Round 5
// 236.318 us; speedup vs baseline: 3.2452x; 1.1374x over previous
//
#include <hip/hip_runtime.h>

// ---------------- problem constants ----------------
constexpr int BATCH = 4;
constexpr int HS    = 64;     // H
constexpr int WSZ   = 64;     // W
constexpr int LSEQ  = 4096;   // L = H*W
constexpr int DM    = 96;     // d_model
constexpr int DI    = 192;    // d_inner
constexpr int NS    = 16;     // d_state
constexpr int RK    = 6;      // dt_rank
constexpr int KD    = 4;      // scan directions
constexpr int NCH   = 128;    // chunks along L
constexpr int CLEN  = 32;     // chunk length
constexpr int XDS   = 160;    // packed xdbl row: 4 * [B(16) C(16) dt(6) pad(2)]

// scan index l -> spatial position p (row-major h*64+w), per direction
__device__ __forceinline__ int pos_of(int k, int l) {
  switch (k & 3) {
    case 0: return l;
    case 1: return ((l & 63) << 6) | (l >> 6);          // l = w*H+h -> p = h*W+w
    case 2: return LSEQ - 1 - l;
    default: { int lp = LSEQ - 1 - l; return ((lp & 63) << 6) | (lp >> 6); }
  }
}

__device__ __forceinline__ float softplus_f(float s) {
  return (s > 20.f) ? s : __logf(1.f + __expf(s));
}

// ---------------- weight transpose: out[c][r] = in[r][c] ----------------
__launch_bounds__(256)
__global__ void transpose_w(const float* __restrict__ in, float* __restrict__ outp,
                            int R, int C_) {
  int idx = blockIdx.x * 256 + threadIdx.x;
  if (idx < R * C_) {
    int r = idx / C_, c = idx % C_;      // coalesced read
    outp[(size_t)c * R + r] = in[idx];   // scattered write (tiny matrix, L2)
  }
}

// ---------------- GEMM: C[M,NN] = A[M,KK] * BT[KK,NN]   (BT pre-transposed) ------
template <int NN, int KK, int TM, int KT>
__launch_bounds__(256)
__global__ void gemm_nt(const float* __restrict__ A, const float* __restrict__ BT,
                        float* __restrict__ C, int M) {
  constexpr int TN  = 64;
  constexpr int RPT = TM / 16;          // rows per thread
  constexpr int SA  = KT + 4;           // padded row stride (words)
  constexpr int KQ  = KT / 4;
  __shared__ float As[TM][SA];
  __shared__ float Bs[KT][TN];
  const int t = threadIdx.x;
  const int row0 = blockIdx.y * TM;
  const int col0 = blockIdx.x * TN;
  const int tc = t & 15;        // 16 col groups * 4 cols
  const int tr = t >> 4;        // 16 row groups * RPT rows

  float acc[RPT][4];
  #pragma unroll
  for (int i = 0; i < RPT; ++i)
    { acc[i][0]=0.f; acc[i][1]=0.f; acc[i][2]=0.f; acc[i][3]=0.f; }

  for (int k0 = 0; k0 < KK; k0 += KT) {
    #pragma unroll 1
    for (int idx = t; idx < TM * KQ; idx += 256) {
      int r = idx / KQ, kq = idx % KQ;
      *(float4*)&As[r][kq * 4] =
          *(const float4*)&A[(size_t)(row0 + r) * KK + k0 + kq * 4];
    }
    #pragma unroll 1
    for (int idx = t; idx < KT * 16; idx += 256) {
      int kk = idx >> 4, cq = idx & 15;
      int col = col0 + cq * 4;
      float4 v = make_float4(0.f, 0.f, 0.f, 0.f);
      if (col < NN) v = *(const float4*)&BT[(size_t)(k0 + kk) * NN + col];
      *(float4*)&Bs[kk][cq * 4] = v;
    }
    __syncthreads();
    #pragma unroll 4
    for (int kk = 0; kk < KT; ++kk) {
      float4 bv = *(const float4*)&Bs[kk][tc * 4];
      #pragma unroll
      for (int i = 0; i < RPT; ++i) {
        float a = As[tr * RPT + i][kk];
        acc[i][0] += a * bv.x; acc[i][1] += a * bv.y;
        acc[i][2] += a * bv.z; acc[i][3] += a * bv.w;
      }
    }
    __syncthreads();
  }
  int c = col0 + tc * 4;
  if (c < NN) {
    #pragma unroll
    for (int i = 0; i < RPT; ++i) {
      size_t r0 = (size_t)(row0 + tr * RPT + i) * NN + c;
      *(float4*)&C[r0] = make_float4(acc[i][0], acc[i][1], acc[i][2], acc[i][3]);
    }
  }
}

// ---------------- depthwise 3x3 conv + bias + SiLU ----------------
__launch_bounds__(256)
__global__ void conv_silu(const float* __restrict__ xz, const float* __restrict__ cw,
                          const float* __restrict__ cb, float* __restrict__ xc) {
  int idx = blockIdx.x * 256 + threadIdx.x;     // over B*L*DI, grid exact
  int d = idx % DI;
  int p = (idx / DI) % LSEQ;
  int b = idx / (DI * LSEQ);
  int h = p >> 6, w = p & 63;
  float acc = cb[d];
  #pragma unroll
  for (int kh = 0; kh < 3; ++kh) {
    int hh = h + kh - 1;
    if ((unsigned)hh >= (unsigned)HS) continue;
    #pragma unroll
    for (int kw = 0; kw < 3; ++kw) {
      int ww = w + kw - 1;
      if ((unsigned)ww >= (unsigned)WSZ) continue;
      acc += xz[((size_t)b * LSEQ + (hh << 6) + ww) * (2 * DI) + d] * cw[d * 9 + kh * 3 + kw];
    }
  }
  xc[idx] = acc / (1.f + __expf(-acc));   // SiLU
}

// ---------------- build packed+transposed weight WcatT[192][160] ----------------
__launch_bounds__(256)
__global__ void build_wcatT(const float* __restrict__ xw, float* __restrict__ WcatT) {
  int idx = blockIdx.x * 256 + threadIdx.x;   // < 192*160, grid exact
  int col = idx / XDS, j = idx % XDS;
  int k = j / 40, jj = j % 40;
  float v = 0.f;
  int src = -1;
  if (jj < 16)      src = k * 38 + 6 + jj;
  else if (jj < 32) src = k * 38 + 22 + (jj - 16);
  else if (jj < 38) src = k * 38 + (jj - 32);
  if (src >= 0) v = xw[(size_t)src * DI + col];
  WcatT[idx] = v;
}

// ---------------- scan phase 1: per-chunk local states + sum(delta); dt fused ----
__launch_bounds__(192)
__global__ void scan_phase1(const float* __restrict__ xc, const float* __restrict__ xdbl,
                            const float* __restrict__ Alog, const float* __restrict__ dtw,
                            const float* __restrict__ dtb,
                            float* __restrict__ hN, float* __restrict__ sumdB) {
  const int d = threadIdx.x;
  const int ch = blockIdx.x, k = blockIdx.y, b = blockIdx.z;
  const int bk = b * KD + k;
  __shared__ float4 Bsh[CLEN * 6];          // per pos: B(q0..3), dt(q8,q9)
  {
    int idx = d;                            // CLEN*6 == 192, one element each
    int j = idx / 6, q = idx % 6;
    int p = pos_of(k, ch * CLEN + j);
    int qq = (q < 4) ? q : (q + 4);
    Bsh[idx] = *(const float4*)&xdbl[(size_t)(b * LSEQ + p) * XDS + k * 40 + qq * 4];
  }
  float An[NS];
  {
    const float4* Ap = (const float4*)&Alog[((size_t)k * DI + d) * NS];
    #pragma unroll
    for (int q = 0; q < 4; ++q) {
      float4 a = Ap[q];
      An[q*4+0] = -__expf(a.x); An[q*4+1] = -__expf(a.y);
      An[q*4+2] = -__expf(a.z); An[q*4+3] = -__expf(a.w);
    }
  }
  float w[RK];
  #pragma unroll
  for (int r = 0; r < RK; ++r) w[r] = dtw[((size_t)k * DI + d) * RK + r];
  const float bsv = dtb[k * DI + d];
  const float An0 = An[0];
  bool geo = true;
  #pragma unroll
  for (int n = 0; n < NS; ++n)
    geo = geo && (fabsf(An[n] - (n + 1) * An0) <= 1e-3f * fabsf(An[n]));
  __syncthreads();

  float h[NS];
  #pragma unroll
  for (int n = 0; n < NS; ++n) h[n] = 0.f;
  float sumd = 0.f;
  const int l0 = ch * CLEN;
  if (geo) {
    #pragma unroll 2
    for (int j = 0; j < CLEN; ++j) {
      const int p = pos_of(k, l0 + j);
      const size_t bp = (size_t)b * LSEQ + p;
      float4 t0 = Bsh[j * 6 + 4], t1 = Bsh[j * 6 + 5];
      float s = bsv + w[0]*t0.x + w[1]*t0.y + w[2]*t0.z + w[3]*t0.w + w[4]*t1.x + w[5]*t1.y;
      float dl = softplus_f(s);
      float du = dl * xc[bp * DI + d];
      float we = __expf(dl * An0), wp = 1.f;
      #pragma unroll
      for (int q = 0; q < 4; ++q) {
        float4 v = Bsh[j * 6 + q];
        wp *= we; h[q*4+0] = wp * h[q*4+0] + du * v.x;
        wp *= we; h[q*4+1] = wp * h[q*4+1] + du * v.y;
        wp *= we; h[q*4+2] = wp * h[q*4+2] + du * v.z;
        wp *= we; h[q*4+3] = wp * h[q*4+3] + du * v.w;
      }
      sumd += dl;
    }
  } else {
    #pragma unroll 1
    for (int j = 0; j < CLEN; ++j) {
      const int p = pos_of(k, l0 + j);
      const size_t bp = (size_t)b * LSEQ + p;
      float4 t0 = Bsh[j * 6 + 4], t1 = Bsh[j * 6 + 5];
      float s = bsv + w[0]*t0.x + w[1]*t0.y + w[2]*t0.z + w[3]*t0.w + w[4]*t1.x + w[5]*t1.y;
      float dl = softplus_f(s);
      float du = dl * xc[bp * DI + d];
      #pragma unroll
      for (int q = 0; q < 4; ++q) {
        float4 v = Bsh[j * 6 + q];
        h[q*4+0] = __expf(dl * An[q*4+0]) * h[q*4+0] + du * v.x;
        h[q*4+1] = __expf(dl * An[q*4+1]) * h[q*4+1] + du * v.y;
        h[q*4+2] = __expf(dl * An[q*4+2]) * h[q*4+2] + du * v.z;
        h[q*4+3] = __expf(dl * An[q*4+3]) * h[q*4+3] + du * v.w;
      }
      sumd += dl;
    }
  }
  const size_t o = ((size_t)bk * NCH + ch) * DI + d;
  float4* Hp = (float4*)&hN[o * NS];
  #pragma unroll
  for (int q = 0; q < 4; ++q)
    Hp[q] = make_float4(h[q*4+0], h[q*4+1], h[q*4+2], h[q*4+3]);
  sumdB[o] = sumd;
}

// ---------------- sequential chunk combine (in-place: hN becomes entry states) ----
__launch_bounds__(256)
__global__ void chunk_combine(float* __restrict__ hN, const float* __restrict__ sumdB,
                              const float* __restrict__ Alog) {
  const int tid = blockIdx.x * 256 + threadIdx.x;   // over B*K*D*N
  const int n  = tid & 15;
  const int dd = tid >> 4;
  const int d  = dd % DI;
  const int bk = dd / DI;
  const int k  = bk & 3;
  const float An = -__expf(Alog[((size_t)k * DI + d) * NS + n]);
  float h = 0.f;
  #pragma unroll 1
  for (int c = 0; c < NCH; ++c) {
    const size_t o = ((size_t)bk * NCH + c) * DI + d;
    float tmp = hN[o * NS + n];
    hN[o * NS + n] = h;
    h = tmp + __expf(An * sumdB[o]) * h;
  }
}

// ---------------- scan phase 2: entry state, emit y (merged via atomics); dt fused --
__launch_bounds__(192)
__global__ void scan_phase2(const float* __restrict__ xc, const float* __restrict__ xdbl,
                            const float* __restrict__ Alog, const float* __restrict__ dtw,
                            const float* __restrict__ dtb, const float* __restrict__ hin,
                            float* __restrict__ yg) {
  const int d = threadIdx.x;
  const int ch = blockIdx.x, k = blockIdx.y, b = blockIdx.z;
  const int bk = b * KD + k;
  __shared__ float4 Bsh[CLEN * 10];         // per pos: B(0..3) C(4..7) dt(8,9)
  #pragma unroll 1
  for (int idx = d; idx < CLEN * 10; idx += 192) {
    int j = idx / 10, q = idx % 10;
    int p = pos_of(k, ch * CLEN + j);
    Bsh[idx] = *(const float4*)&xdbl[(size_t)(b * LSEQ + p) * XDS + k * 40 + q * 4];
  }
  float An[NS];
  {
    const float4* Ap = (const float4*)&Alog[((size_t)k * DI + d) * NS];
    #pragma unroll
    for (int q = 0; q < 4; ++q) {
      float4 a = Ap[q];
      An[q*4+0] = -__expf(a.x); An[q*4+1] = -__expf(a.y);
      An[q*4+2] = -__expf(a.z); An[q*4+3] = -__expf(a.w);
    }
  }
  float w[RK];
  #pragma unroll
  for (int r = 0; r < RK; ++r) w[r] = dtw[((size_t)k * DI + d) * RK + r];
  const float bsv = dtb[k * DI + d];
  const float An0 = An[0];
  bool geo = true;
  #pragma unroll
  for (int n = 0; n < NS; ++n)
    geo = geo && (fabsf(An[n] - (n + 1) * An0) <= 1e-3f * fabsf(An[n]));

  float h[NS];
  {
    const size_t o = ((size_t)bk * NCH + ch) * DI + d;
    const float4* Hp = (const float4*)&hin[o * NS];
    #pragma unroll
    for (int q = 0; q < 4; ++q) {
      float4 v = Hp[q];
      h[q*4+0] = v.x; h[q*4+1] = v.y; h[q*4+2] = v.z; h[q*4+3] = v.w;
    }
  }
  __syncthreads();
  const int l0 = ch * CLEN;
  if (geo) {
    #pragma unroll 2
    for (int j = 0; j < CLEN; ++j) {
      const int p = pos_of(k, l0 + j);
      const size_t bp = (size_t)b * LSEQ + p;
      float4 t0 = Bsh[j * 10 + 8], t1 = Bsh[j * 10 + 9];
      float s = bsv + w[0]*t0.x + w[1]*t0.y + w[2]*t0.z + w[3]*t0.w + w[4]*t1.x + w[5]*t1.y;
      float dl = softplus_f(s);
      float du = dl * xc[bp * DI + d];
      float we = __expf(dl * An0), wp = 1.f;
      float y = 0.f;
      #pragma unroll
      for (int q = 0; q < 4; ++q) {
        float4 v  = Bsh[j * 10 + q];
        float4 c4 = Bsh[j * 10 + 4 + q];
        wp *= we; h[q*4+0] = wp * h[q*4+0] + du * v.x; y += h[q*4+0] * c4.x;
        wp *= we; h[q*4+1] = wp * h[q*4+1] + du * v.y; y += h[q*4+1] * c4.y;
        wp *= we; h[q*4+2] = wp * h[q*4+2] + du * v.z; y += h[q*4+2] * c4.z;
        wp *= we; h[q*4+3] = wp * h[q*4+3] + du * v.w; y += h[q*4+3] * c4.w;
      }
      atomicAdd(&yg[bp * DI + d], y);
    }
  } else {
    #pragma unroll 1
    for (int j = 0; j < CLEN; ++j) {
      const int p = pos_of(k, l0 + j);
      const size_t bp = (size_t)b * LSEQ + p;
      float4 t0 = Bsh[j * 10 + 8], t1 = Bsh[j * 10 + 9];
      float s = bsv + w[0]*t0.x + w[1]*t0.y + w[2]*t0.z + w[3]*t0.w + w[4]*t1.x + w[5]*t1.y;
      float dl = softplus_f(s);
      float du = dl * xc[bp * DI + d];
      float y = 0.f;
      #pragma unroll
      for (int q = 0; q < 4; ++q) {
        float4 v  = Bsh[j * 10 + q];
        float4 c4 = Bsh[j * 10 + 4 + q];
        h[q*4+0] = __expf(dl * An[q*4+0]) * h[q*4+0] + du * v.x; y += h[q*4+0] * c4.x;
        h[q*4+1] = __expf(dl * An[q*4+1]) * h[q*4+1] + du * v.y; y += h[q*4+1] * c4.y;
        h[q*4+2] = __expf(dl * An[q*4+2]) * h[q*4+2] + du * v.z; y += h[q*4+2] * c4.z;
        h[q*4+3] = __expf(dl * An[q*4+3]) * h[q*4+3] + du * v.w; y += h[q*4+3] * c4.w;
      }
      atomicAdd(&yg[bp * DI + d], y);
    }
  }
}

// ---------------- direction merge (Ds term) + LayerNorm + SiLU gate ----------------
__launch_bounds__(192)
__global__ void fuse_ln(const float* __restrict__ yg, const float* __restrict__ xc,
                        const float* __restrict__ Ds, const float* __restrict__ xz,
                        const float* __restrict__ lnw, const float* __restrict__ lnb,
                        float* __restrict__ ymul) {
  const int row = blockIdx.x;        // b*L + p
  const int d = threadIdx.x;
  float u = xc[(size_t)row * DI + d];
  float sDs = Ds[d] + Ds[DI + d] + Ds[2 * DI + d] + Ds[3 * DI + d];
  float y = yg[(size_t)row * DI + d] + sDs * u;
  float s1 = y, s2 = y * y;
  #pragma unroll
  for (int off = 32; off; off >>= 1) {
    s1 += __shfl_xor(s1, off);
    s2 += __shfl_xor(s2, off);
  }
  __shared__ float r1[3], r2[3];
  int wid = d >> 6;
  if ((d & 63) == 0) { r1[wid] = s1; r2[wid] = s2; }
  __syncthreads();
  float S1 = r1[0] + r1[1] + r1[2];
  float S2 = r2[0] + r2[1] + r2[2];
  float mu = S1 * (1.f / DI);
  float var = S2 * (1.f / DI) - mu * mu;
  float yn = (y - mu) * rsqrtf(var + 1e-5f) * lnw[d] + lnb[d];
  float zv = xz[(size_t)row * (2 * DI) + DI + d];
  float g = zv / (1.f + __expf(-zv));
  ymul[(size_t)row * DI + d] = yn * g;
}

// ---------------- launcher ----------------
extern "C" void kernel_launch(void* const* d_in, const int* in_sizes, int n_in,
                              void* d_out, int out_size, void* d_ws, size_t ws_size,
                              hipStream_t stream) {
  (void)in_sizes; (void)n_in; (void)out_size; (void)ws_size;
  const float* x          = (const float*)d_in[0];
  const float* in_proj_w  = (const float*)d_in[1];
  const float* conv_w     = (const float*)d_in[2];
  const float* conv_b     = (const float*)d_in[3];
  const float* x_proj_w   = (const float*)d_in[4];
  const float* dt_w       = (const float*)d_in[5];
  const float* dt_b       = (const float*)d_in[6];
  const float* A_logs     = (const float*)d_in[7];
  const float* Ds         = (const float*)d_in[8];
  const float* ln_w       = (const float*)d_in[9];
  const float* ln_b       = (const float*)d_in[10];
  const float* out_proj_w = (const float*)d_in[11];
  float* out = (float*)d_out;
  float* ws  = (float*)d_ws;

  constexpr size_t SZ_XZ    = (size_t)BATCH * LSEQ * 2 * DI;
  constexpr size_t SZ_XC    = (size_t)BATCH * LSEQ * DI;
  constexpr size_t SZ_XD    = (size_t)BATCH * LSEQ * XDS;
  constexpr size_t SZ_HN    = (size_t)BATCH * KD * NCH * DI * NS;
  constexpr size_t SZ_SUMD  = (size_t)BATCH * KD * NCH * DI;

  float* xz    = ws;
  float* xc    = xz + SZ_XZ;
  float* xdbl  = xc + SZ_XC;
  float* hN    = xdbl + SZ_XD;
  float* sumd  = hN + SZ_HN;
  float* yg    = sumd + SZ_SUMD;
  float* ymul  = yg + SZ_XC;
  float* WcatT = ymul + SZ_XC;                  // [192][160]
  float* inpT  = WcatT + (size_t)DI * XDS;      // [96][384]
  float* outpT = inpT + (size_t)DM * 2 * DI;    // [192][96]

  const int M = BATCH * LSEQ;  // 16384

  // 0. weight prep (transposes + packed Wcat^T)
  build_wcatT<<<(DI * XDS) / 256, 256, 0, stream>>>(x_proj_w, WcatT);
  transpose_w<<<(2 * DI * DM + 255) / 256, 256, 0, stream>>>(in_proj_w, inpT, 2 * DI, DM);
  transpose_w<<<(DM * DI + 255) / 256, 256, 0, stream>>>(out_proj_w, outpT, DM, DI);
  // 1. in_proj: xz[M,384] = x[M,96] @ inpT[96,384]
  gemm_nt<2 * DI, DM, 64, 96><<<dim3(6, M / 64), 256, 0, stream>>>(x, inpT, xz, M);
  // 2. depthwise conv + SiLU -> xc (B,L,D)
  conv_silu<<<(BATCH * LSEQ * DI) / 256, 256, 0, stream>>>(xz, conv_w, conv_b, xc);
  // 3. x_proj all directions, position space: xdbl[M,160] = xc[M,192] @ WcatT[192,160]
  gemm_nt<XDS, DI, 64, 96><<<dim3(3, M / 64), 256, 0, stream>>>(xc, WcatT, xdbl, M);
  // 4. scan phase 1 (dt fused)
  scan_phase1<<<dim3(NCH, KD, BATCH), 192, 0, stream>>>(xc, xdbl, A_logs, dt_w, dt_b,
                                                        hN, sumd);
  // 5. chunk combine (in-place: hN -> entry states)
  chunk_combine<<<(BATCH * KD * DI * NS) / 256, 256, 0, stream>>>(hN, sumd, A_logs);
  // 6. scan phase 2 -> yg (merged over directions; dt fused)
  hipMemsetAsync(yg, 0, SZ_XC * sizeof(float), stream);
  scan_phase2<<<dim3(NCH, KD, BATCH), 192, 0, stream>>>(xc, xdbl, A_logs, dt_w, dt_b,
                                                        hN, yg);
  // 7. merge + LN + gate -> ymul
  fuse_ln<<<M, DI, 0, stream>>>(yg, xc, Ds, xz, ln_w, ln_b, ymul);
  // 8. out_proj: out[M,96] = ymul[M,192] @ outpT[192,96]
  gemm_nt<DM, DI, 64, 96><<<dim3(2, M / 64), 256, 0, stream>>>(ymul, outpT, out, M);
}